// Round 11
// baseline (371.900 us; speedup 1.0000x reference)
//
#include <hip/hip_runtime.h>
#include <hip/hip_bf16.h>

typedef unsigned short u16;
typedef __attribute__((ext_vector_type(8))) short bf16x8;
typedef __attribute__((ext_vector_type(4))) float f32x4;
typedef __attribute__((ext_vector_type(8))) u16 u16x8;
typedef __attribute__((ext_vector_type(4))) u16 u16x4;

#define T_SEQ 2048
#define HID 4096
#define NQ 32
#define NKV 8
#define DH 128
#define WIN 1024

__device__ __forceinline__ u16 f2bf(float f) {
  union { float f; unsigned int u; } v; v.f = f;
  unsigned int u = v.u;
  unsigned int r = (u + 0x7FFFu + ((u >> 16) & 1u)) >> 16;
  return (u16)r;
}
__device__ __forceinline__ float bf2f(u16 b) {
  union { unsigned int u; float f; } v; v.u = ((unsigned int)b) << 16;
  return v.f;
}

__device__ __forceinline__ void gload16(const void* g, void* l) {
  __builtin_amdgcn_global_load_lds(
      (const __attribute__((address_space(1))) unsigned int*)g,
      (__attribute__((address_space(3))) unsigned int*)l, 16, 0, 0);
}

// ---------------- elementwise f32 -> bf16 ----------------
__global__ __launch_bounds__(256) void f32_to_bf16(const float* __restrict__ in,
                                                   u16* __restrict__ out, int n) {
  int i = (blockIdx.x * 256 + threadIdx.x) * 8;
  if (i >= n) return;
  float4 a = *(const float4*)(in + i);
  float4 b = *(const float4*)(in + i + 4);
  u16x8 r;
  r[0] = f2bf(a.x); r[1] = f2bf(a.y); r[2] = f2bf(a.z); r[3] = f2bf(a.w);
  r[4] = f2bf(b.x); r[5] = f2bf(b.y); r[6] = f2bf(b.z); r[7] = f2bf(b.w);
  *(u16x8*)(out + i) = r;
}

// ---------------- tiled transpose f32 (R x C) -> bf16 (C x R) ----------------
__global__ __launch_bounds__(256) void transpose_f32_to_bf16(const float* __restrict__ in,
                                                             u16* __restrict__ out,
                                                             int R, int C) {
  __shared__ float tile[32][33];
  int c0 = blockIdx.x * 32, r0 = blockIdx.y * 32;
  int tx = threadIdx.x, ty = threadIdx.y;
  for (int i = 0; i < 32; i += 8)
    tile[ty + i][tx] = in[(size_t)(r0 + ty + i) * C + c0 + tx];
  __syncthreads();
  for (int i = 0; i < 32; i += 8)
    out[(size_t)(c0 + ty + i) * R + r0 + tx] = f2bf(tile[tx][ty + i]);
}

// ---------------- 256xBN 4-phase full-fill GEMM (R6-proven schedule) ----------------
// C(MxN) = A(bf16 MxK rm) * Bt(bf16 NxK rm)^T.  BM=256, BN=NF*64, BK=64.
// 8 waves 4Mx2N; 4 phases/tile, quadrant = (mh: 2mf) x (nh: NF nf).
// Stage units of 8KB (512 thr x 16B): A=4/tile, B=NB=BN/64 per tile.
// P1: rd afA+bfr0, stage A(t+1)u01 [slot^1]; P2: rd bfr1, stage A(t+1)u23;
// P3: rd afB, stage B(t+2) units 0..NB-2 [slot]; P4: stage B(t+2) last unit,
// vmcnt(NB) -> A(t+1)+B(t+1) resident, B(t+2) still flying.
// Swizzle chunk ^= row&7 (128B rows), pre-swizzled source (both sides).
template <int NF, bool BF16OUT>
__global__ __launch_bounds__(512, 2) void gemm_np(const u16* __restrict__ A,
                                                  const u16* __restrict__ Bt,
                                                  void* __restrict__ Cv,
                                                  int N, int K, int NT) {
  constexpr int HN = NF * 16;
  constexpr int BN = 4 * HN;
  constexpr int NB = BN / 64;
  __shared__ u16 lsA[2][16384];
  __shared__ u16 lsB[2][BN * 64];
  const int tid = threadIdx.x;
  const int lane = tid & 63, w = tid >> 6;
  const int wm = w >> 1, wn = w & 1;
  const int l15 = lane & 15, l4 = lane >> 4;

  const int nwg = gridDim.x;
  const int cpx = nwg >> 3;
  const int bid = blockIdx.x;
  const int swz = (bid & 7) * cpx + (bid >> 3);
  const int bm = (swz & 7) * 256;
  const int bn = (swz >> 3) * BN;

  auto stageA = [&](int unit, int slot, int kt) {
    int r = tid >> 3, cp = tid & 7;
    int scp = cp ^ (r & 7);
    gload16(A + (size_t)(bm + unit * 64 + r) * K + kt * 64 + scp * 8,
            (char*)lsA[slot] + (unit * 512 + tid) * 16);
  };
  auto stageB = [&](int unit, int slot, int kt) {
    int r = tid >> 3, cp = tid & 7;
    int scp = cp ^ (r & 7);
    gload16(Bt + (size_t)(bn + unit * 64 + r) * K + kt * 64 + scp * 8,
            (char*)lsB[slot] + (unit * 512 + tid) * 16);
  };
  auto rdA = [&](int slot, int mh, int mf, int ks) -> bf16x8 {
    int r = wm * 64 + mh * 32 + mf * 16 + l15;
    int ch = (ks * 4 + l4) ^ (r & 7);
    return *(const bf16x8*)(lsA[slot] + r * 64 + ch * 8);
  };
  auto rdB = [&](int slot, int nh, int nf, int ks) -> bf16x8 {
    int r = wn * 2 * HN + nh * HN + nf * 16 + l15;
    int ch = (ks * 4 + l4) ^ (r & 7);
    return *(const bf16x8*)(lsB[slot] + r * 64 + ch * 8);
  };

#define WAIT_NB() do { if constexpr (NB == 3) asm volatile("s_waitcnt vmcnt(3)" ::: "memory"); \
                       else                   asm volatile("s_waitcnt vmcnt(2)" ::: "memory"); } while (0)

  f32x4 acc[4][2 * NF] = {};
  bf16x8 afA[2][2], afB[2][2], bfr0[NF][2], bfr1[NF][2];

  stageA(0, 0, 0); stageA(1, 0, 0); stageA(2, 0, 0); stageA(3, 0, 0);
#pragma unroll
  for (int u = 0; u < NB; ++u) stageB(u, 0, 0);
#pragma unroll
  for (int u = 0; u < NB; ++u) stageB(u, 1, 1);
  WAIT_NB();
  __builtin_amdgcn_s_barrier();

  for (int t = 0; t < NT; ++t) {
    const int s = t & 1;
    const int ktA = (t + 1 < NT) ? t + 1 : NT - 1;
    const int ktB = (t + 2 < NT) ? t + 2 : NT - 1;

    // ---- P1 ----
#pragma unroll
    for (int mf = 0; mf < 2; ++mf)
#pragma unroll
      for (int ks = 0; ks < 2; ++ks) afA[mf][ks] = rdA(s, 0, mf, ks);
#pragma unroll
    for (int nf = 0; nf < NF; ++nf)
#pragma unroll
      for (int ks = 0; ks < 2; ++ks) bfr0[nf][ks] = rdB(s, 0, nf, ks);
    stageA(0, s ^ 1, ktA); stageA(1, s ^ 1, ktA);
    __builtin_amdgcn_s_barrier();
    asm volatile("s_waitcnt lgkmcnt(0)" ::: "memory");
    __builtin_amdgcn_sched_barrier(0);
    __builtin_amdgcn_s_setprio(1);
#pragma unroll
    for (int mf = 0; mf < 2; ++mf)
#pragma unroll
      for (int nf = 0; nf < NF; ++nf) {
        acc[mf][nf] = __builtin_amdgcn_mfma_f32_16x16x32_bf16(afA[mf][0], bfr0[nf][0], acc[mf][nf], 0, 0, 0);
        acc[mf][nf] = __builtin_amdgcn_mfma_f32_16x16x32_bf16(afA[mf][1], bfr0[nf][1], acc[mf][nf], 0, 0, 0);
      }
    __builtin_amdgcn_s_setprio(0);
    __builtin_amdgcn_s_barrier();

    // ---- P2 ----
#pragma unroll
    for (int nf = 0; nf < NF; ++nf)
#pragma unroll
      for (int ks = 0; ks < 2; ++ks) bfr1[nf][ks] = rdB(s, 1, nf, ks);
    stageA(2, s ^ 1, ktA); stageA(3, s ^ 1, ktA);
    __builtin_amdgcn_s_barrier();
    asm volatile("s_waitcnt lgkmcnt(0)" ::: "memory");
    __builtin_amdgcn_sched_barrier(0);
    __builtin_amdgcn_s_setprio(1);
#pragma unroll
    for (int mf = 0; mf < 2; ++mf)
#pragma unroll
      for (int nf = 0; nf < NF; ++nf) {
        acc[mf][NF + nf] = __builtin_amdgcn_mfma_f32_16x16x32_bf16(afA[mf][0], bfr1[nf][0], acc[mf][NF + nf], 0, 0, 0);
        acc[mf][NF + nf] = __builtin_amdgcn_mfma_f32_16x16x32_bf16(afA[mf][1], bfr1[nf][1], acc[mf][NF + nf], 0, 0, 0);
      }
    __builtin_amdgcn_s_setprio(0);
    __builtin_amdgcn_s_barrier();

    // ---- P3 ----
#pragma unroll
    for (int mf = 0; mf < 2; ++mf)
#pragma unroll
      for (int ks = 0; ks < 2; ++ks) afB[mf][ks] = rdA(s, 1, mf, ks);
#pragma unroll
    for (int u = 0; u < NB - 1; ++u) stageB(u, s, ktB);
    __builtin_amdgcn_s_barrier();
    asm volatile("s_waitcnt lgkmcnt(0)" ::: "memory");
    __builtin_amdgcn_sched_barrier(0);
    __builtin_amdgcn_s_setprio(1);
#pragma unroll
    for (int mf = 0; mf < 2; ++mf)
#pragma unroll
      for (int nf = 0; nf < NF; ++nf) {
        acc[2 + mf][nf] = __builtin_amdgcn_mfma_f32_16x16x32_bf16(afB[mf][0], bfr0[nf][0], acc[2 + mf][nf], 0, 0, 0);
        acc[2 + mf][nf] = __builtin_amdgcn_mfma_f32_16x16x32_bf16(afB[mf][1], bfr0[nf][1], acc[2 + mf][nf], 0, 0, 0);
      }
    __builtin_amdgcn_s_setprio(0);
    __builtin_amdgcn_s_barrier();

    // ---- P4 ----
    stageB(NB - 1, s, ktB);
    __builtin_amdgcn_s_barrier();
    __builtin_amdgcn_s_setprio(1);
#pragma unroll
    for (int mf = 0; mf < 2; ++mf)
#pragma unroll
      for (int nf = 0; nf < NF; ++nf) {
        acc[2 + mf][NF + nf] = __builtin_amdgcn_mfma_f32_16x16x32_bf16(afB[mf][0], bfr1[nf][0], acc[2 + mf][NF + nf], 0, 0, 0);
        acc[2 + mf][NF + nf] = __builtin_amdgcn_mfma_f32_16x16x32_bf16(afB[mf][1], bfr1[nf][1], acc[2 + mf][NF + nf], 0, 0, 0);
      }
    __builtin_amdgcn_s_setprio(0);
    WAIT_NB();
    __builtin_amdgcn_s_barrier();
  }

  asm volatile("s_waitcnt vmcnt(0)" ::: "memory");

#pragma unroll
  for (int mi = 0; mi < 4; ++mi)
#pragma unroll
    for (int ni = 0; ni < 2 * NF; ++ni) {
      int row = bm + wm * 64 + mi * 16 + l4 * 4;
      int col = bn + wn * 2 * HN + ni * 16 + l15;
      if constexpr (BF16OUT) {
        u16* dst = (u16*)Cv;
#pragma unroll
        for (int j = 0; j < 4; ++j)
          dst[(size_t)(row + j) * N + col] = f2bf(acc[mi][ni][j]);
      } else {
        float* p = (float*)Cv + (size_t)row * N + col;
        p[0] = acc[mi][ni][0];
        p[(size_t)N] = acc[mi][ni][1];
        p[2 * (size_t)N] = acc[mi][ni][2];
        p[3 * (size_t)N] = acc[mi][ni][3];
      }
    }
#undef WAIT_NB
}

// ---------------- RMSNorm + RoPE + layout (bf16 qkv in; Q scaled; V transposed) -------
__global__ __launch_bounds__(256) void rope_kernel(const u16* __restrict__ qkv,
                                                   const float* __restrict__ cosb,
                                                   const float* __restrict__ sinb,
                                                   const float* __restrict__ qw,
                                                   const float* __restrict__ kw,
                                                   u16* __restrict__ Qo,
                                                   u16* __restrict__ Ko,
                                                   u16* __restrict__ Vt) {
  int wid = threadIdx.x >> 6, lane = threadIdx.x & 63;
  int item = blockIdx.x * 4 + wid;          // item = t*48 + hid
  int t = item / 48, hid = item % 48;
  const u16* x = qkv + (size_t)t * 6144 + hid * 128;
  float x1 = bf2f(x[lane]), x2 = bf2f(x[lane + 64]);
  if (hid < NQ + NKV) {
    float ss = x1 * x1 + x2 * x2;
    for (int off = 32; off; off >>= 1) ss += __shfl_xor(ss, off);
    float inv = rsqrtf(ss * (1.0f / 128.0f) + 1e-6f);
    const float* wn = (hid < NQ) ? qw : kw;
    float n1 = x1 * inv * wn[lane], n2 = x2 * inv * wn[lane + 64];
    float c1 = cosb[t * 128 + lane], s1 = sinb[t * 128 + lane];
    float c2 = cosb[t * 128 + lane + 64], s2 = sinb[t * 128 + lane + 64];
    float o1 = n1 * c1 - n2 * s1;
    float o2 = n2 * c2 + n1 * s2;
    if (hid < NQ) {
      const float scale = 0.08838834764831845f;  // fold 1/sqrt(128) into Q
      u16* q = Qo + ((size_t)hid * T_SEQ + t) * 128;
      q[lane] = f2bf(o1 * scale); q[lane + 64] = f2bf(o2 * scale);
    } else {
      int h = hid - NQ;
      u16* k = Ko + ((size_t)h * T_SEQ + t) * 128;
      k[lane] = f2bf(o1); k[lane + 64] = f2bf(o2);
    }
  } else {
    int h = hid - (NQ + NKV);
    Vt[((size_t)h * 128 + lane) * T_SEQ + t] = x[lane];
    Vt[((size_t)h * 128 + lane + 64) * T_SEQ + t] = x[lane + 64];
  }
}

// ---------------- flash attention: 4 waves/block, QBLK=128 (2x16 rows/wave), KVBLK=64 ----
// Wave w owns q in [q0 + w*32, q0 + w*32 + 32), processed as two sequential
// 16-row halves qh=0,1 around the proven R9 tile body. Halves the number of
// blocks (512) -> K/V staging traffic and stage-issue work halve; MFMA per
// barrier-window doubles (QK16+PV16 per qh). Dbuf/vmcnt(8)/barrier structure
// identical to R9. LDS 73KB -> 2 blocks/CU; grid 32x16 = 512 = 2/CU resident.
// K LDS rows 256B: swz col ^= row&7. V^T LDS rows 128B: swz ch ^= d&7.
__global__ __launch_bounds__(256) void attn_kernel(const u16* __restrict__ Q,
                                                   const u16* __restrict__ Kb,
                                                   const u16* __restrict__ Vt,
                                                   u16* __restrict__ O) {
  __shared__ u16 kls[2][64 * 128];   // 16KB per buf
  __shared__ u16 vls[2][128 * 64];   // 16KB per buf
  __shared__ u16 plds[4][16 * 72];   // per-wave P [16 q][64 k] pad to 72

  const int tid = threadIdx.x;
  const int lane = tid & 63, w = tid >> 6;
  const int l15 = lane & 15, l4 = lane >> 4;
  const int h = blockIdx.x;          // q head
  const int q0 = blockIdx.y * 128;   // block q base
  const int wq0 = q0 + w * 32;       // wave q base (32 rows)
  const int kvh = h >> 2;

  bf16x8 qf[2][4];
#pragma unroll
  for (int qh = 0; qh < 2; ++qh) {
    const u16* qrow = Q + ((size_t)h * T_SEQ + (wq0 + qh * 16 + l15)) * DH;
#pragma unroll
    for (int ks = 0; ks < 4; ++ks)
      qf[qh][ks] = *(const bf16x8*)(qrow + ks * 32 + l4 * 8);
  }

  f32x4 acc[2][8] = {};
  float m[2] = {-1e30f, -1e30f}, lsum[2] = {0.f, 0.f};

  int ks0 = q0 - (WIN - 1); if (ks0 < 0) ks0 = 0;
  ks0 &= ~63;
  const int kend = q0 + 64;          // tile [q0+64, q0+127] covers the diagonal

  auto stage = [&](int b, int k0) {
#pragma unroll
    for (int c = 0; c < 4; ++c) {
      int base = w * 4096 + c * 1024;            // bytes in 16KB tile
      int idx = base / 16 + lane;                // 16B chunk index 0..1023
      {
        int row = idx >> 4;                      // K row (64 rows x 256B)
        int col = (idx & 15) ^ (row & 7);
        gload16(Kb + ((size_t)kvh * T_SEQ + k0 + row) * DH + col * 8,
                (char*)kls[b] + base);
      }
      {
        int d = idx >> 3;                        // V^T row (128 rows x 128B)
        int ch = (idx & 7) ^ (d & 7);
        gload16(Vt + ((size_t)kvh * DH + d) * T_SEQ + k0 + ch * 8,
                (char*)vls[b] + base);
      }
    }
  };

  stage(0, ks0);
  int buf = 0;
  for (int k0 = ks0; k0 <= kend; k0 += 64) {
    bool more = (k0 + 64 <= kend);
    if (more) stage(buf ^ 1, k0 + 64);
    if (more) { asm volatile("s_waitcnt vmcnt(8)" ::: "memory"); }
    else      { asm volatile("s_waitcnt vmcnt(0)" ::: "memory"); }
    __builtin_amdgcn_s_barrier();
    __builtin_amdgcn_sched_barrier(0);

#pragma unroll
    for (int qh = 0; qh < 2; ++qh) {
      const int wqq = wq0 + qh * 16;
      // qh-level skip: does [k0, k0+63] intersect [wqq-1023, wqq+15]?
      if (k0 > wqq + 15 || k0 + 63 < wqq - (WIN - 1)) continue;

      // ---- QK^T (swapped): S^T[k][q], A=K from LDS, B=Q regs ----
      f32x4 st[4];
#pragma unroll
      for (int kh = 0; kh < 4; ++kh) {
        f32x4 s = {};
        int row = kh * 16 + l15;
        const char* kb = (const char*)kls[buf] + row * 256;
#pragma unroll
        for (int ks = 0; ks < 4; ++ks) {
          int chunk = (ks * 4 + l4) ^ (row & 7);
          bf16x8 kf = *(const bf16x8*)(kb + chunk * 16);
          s = __builtin_amdgcn_mfma_f32_16x16x32_bf16(kf, qf[qh][ks], s, 0, 0, 0);
        }
        st[kh] = s;
      }
      // ---- mask + online softmax (lane owns q = wqq+l15) ----
      const int q = wqq + l15;
      float pv[4][4];
      float mx = -3e38f;
#pragma unroll
      for (int kh = 0; kh < 4; ++kh)
#pragma unroll
        for (int i = 0; i < 4; ++i) {
          int k = k0 + kh * 16 + l4 * 4 + i;
          bool ok = ((k >> 2) <= (q >> 2)) && (q - k < WIN);
          float s = ok ? st[kh][i] : -3e38f;
          pv[kh][i] = s;
          mx = fmaxf(mx, s);
        }
      mx = fmaxf(mx, __shfl_xor(mx, 16));
      mx = fmaxf(mx, __shfl_xor(mx, 32));
      if (!__all(mx <= m[qh] + 8.f)) {      // defer-max
        float mn = fmaxf(m[qh], mx);
        float sc = __expf(m[qh] - mn);
        m[qh] = mn;
        lsum[qh] *= sc;
#pragma unroll
        for (int nt = 0; nt < 8; ++nt)
#pragma unroll
          for (int i = 0; i < 4; ++i) acc[qh][nt][i] *= sc;
      }
      float rs = 0.f;
#pragma unroll
      for (int kh = 0; kh < 4; ++kh)
#pragma unroll
        for (int i = 0; i < 4; ++i) {
          float p = __expf(pv[kh][i] - m[qh]);
          pv[kh][i] = p;
          rs += p;
        }
      rs += __shfl_xor(rs, 16);
      rs += __shfl_xor(rs, 32);
      lsum[qh] += rs;
      // ---- pack P -> per-wave LDS [16 q][64 k] ----
      u16* pw = plds[w];
#pragma unroll
      for (int kh = 0; kh < 4; ++kh) {
        unsigned int d0 = (unsigned int)f2bf(pv[kh][0]) | ((unsigned int)f2bf(pv[kh][1]) << 16);
        unsigned int d1 = (unsigned int)f2bf(pv[kh][2]) | ((unsigned int)f2bf(pv[kh][3]) << 16);
        *(unsigned int*)(pw + l15 * 72 + kh * 16 + l4 * 4) = d0;
        *(unsigned int*)(pw + l15 * 72 + kh * 16 + l4 * 4 + 2) = d1;
      }
      bf16x8 pf0 = *(const bf16x8*)(pw + l15 * 72 + l4 * 8);
      bf16x8 pf1 = *(const bf16x8*)(pw + l15 * 72 + 32 + l4 * 8);
      // ---- PV: O^T += V^T * P^T (A = V^T from LDS, B = P), 2 K=32 halves ----
#pragma unroll
      for (int nt = 0; nt < 8; ++nt) {
        int d = nt * 16 + l15;
        int ch0 = l4 ^ (d & 7);
        int ch1 = (4 + l4) ^ (d & 7);
        bf16x8 vf0 = *(const bf16x8*)((const char*)vls[buf] + d * 128 + ch0 * 16);
        bf16x8 vf1 = *(const bf16x8*)((const char*)vls[buf] + d * 128 + ch1 * 16);
        acc[qh][nt] = __builtin_amdgcn_mfma_f32_16x16x32_bf16(vf0, pf0, acc[qh][nt], 0, 0, 0);
        acc[qh][nt] = __builtin_amdgcn_mfma_f32_16x16x32_bf16(vf1, pf1, acc[qh][nt], 0, 0, 0);
      }
    }
    __builtin_amdgcn_sched_barrier(0);
    __builtin_amdgcn_s_barrier();
    buf ^= 1;
  }

  // ---- epilogue ----
#pragma unroll
  for (int qh = 0; qh < 2; ++qh) {
    float inv = 1.0f / lsum[qh];
#pragma unroll
    for (int nt = 0; nt < 8; ++nt) {
      u16x4 o;
#pragma unroll
      for (int i = 0; i < 4; ++i) o[i] = f2bf(acc[qh][nt][i] * inv);
      *(u16x4*)(O + (size_t)(wq0 + qh * 16 + l15) * (NQ * DH) + h * DH + nt * 16 + l4 * 4) = o;
    }
  }
}

extern "C" void kernel_launch(void* const* d_in, const int* in_sizes, int n_in,
                              void* d_out, int out_size, void* d_ws, size_t ws_size,
                              hipStream_t stream) {
  const float* hidden = (const float*)d_in[0];
  const float* cosb   = (const float*)d_in[1];
  const float* sinb   = (const float*)d_in[2];
  const float* w_qkv  = (const float*)d_in[3];
  const float* qnw    = (const float*)d_in[4];
  const float* knw    = (const float*)d_in[5];
  const float* w_o    = (const float*)d_in[6];
  float* out = (float*)d_out;
  char* ws = (char*)d_ws;

  u16*   wqkvT  = (u16*)(ws);                        // [0, 48M)
  u16*   hid_bf = (u16*)(ws + ((size_t)48 << 20));   // [48M, 64M)
  u16*   qkv_bf = (u16*)(ws + ((size_t)64 << 20));   // [64M, 88M) bf16 qkv (24MB)
  u16*   q_bf   = (u16*)(ws + ((size_t)112 << 20));  // 16MB
  u16*   k_bf   = (u16*)(ws + ((size_t)128 << 20));  // 4MB
  u16*   vt_bf  = (u16*)(ws + ((size_t)132 << 20));  // 4MB
  u16*   attn_bf= (u16*)(ws + ((size_t)48 << 20));   // reuse hid_bf region
  u16*   woT    = (u16*)(ws);                        // reuse wqkvT region

  f32_to_bf16<<<4096, 256, 0, stream>>>(hidden, hid_bf, T_SEQ * HID);
  transpose_f32_to_bf16<<<dim3(192, 128), dim3(32, 8), 0, stream>>>(w_qkv, wqkvT, HID, 6144);
  // gemm1: 2048x6144x4096, BN=192 -> grid 8x32 = 256 blocks (full fill), bf16 out
  gemm_np<3, true><<<256, 512, 0, stream>>>(hid_bf, wqkvT, qkv_bf, 6144, HID, 64);
  transpose_f32_to_bf16<<<dim3(128, 128), dim3(32, 8), 0, stream>>>(w_o, woT, NQ * DH, HID);
  rope_kernel<<<(T_SEQ * 48) / 4, 256, 0, stream>>>(qkv_bf, cosb, sinb, qnw, knw, q_bf, k_bf, vt_bf);
  attn_kernel<<<dim3(NQ, T_SEQ / 128), 256, 0, stream>>>(q_bf, k_bf, vt_bf, attn_bf);
  // gemm2: 2048x4096x4096, BN=128 -> grid 8x32 = 256 blocks (full fill), f32 out
  gemm_np<2, false><<<256, 512, 0, stream>>>(attn_bf, woT, out, HID, NQ * DH, 64);
}

// Round 12
// 330.202 us; speedup vs baseline: 1.1263x; 1.1263x over previous
//
#include <hip/hip_runtime.h>
#include <hip/hip_bf16.h>

typedef unsigned short u16;
typedef __attribute__((ext_vector_type(8))) short bf16x8;
typedef __attribute__((ext_vector_type(4))) float f32x4;
typedef __attribute__((ext_vector_type(8))) u16 u16x8;
typedef __attribute__((ext_vector_type(4))) u16 u16x4;

#define T_SEQ 2048
#define HID 4096
#define NQ 32
#define NKV 8
#define DH 128
#define WIN 1024

__device__ __forceinline__ u16 f2bf(float f) {
  union { float f; unsigned int u; } v; v.f = f;
  unsigned int u = v.u;
  unsigned int r = (u + 0x7FFFu + ((u >> 16) & 1u)) >> 16;
  return (u16)r;
}
__device__ __forceinline__ float bf2f(u16 b) {
  union { unsigned int u; float f; } v; v.u = ((unsigned int)b) << 16;
  return v.f;
}

__device__ __forceinline__ void gload16(const void* g, void* l) {
  __builtin_amdgcn_global_load_lds(
      (const __attribute__((address_space(1))) unsigned int*)g,
      (__attribute__((address_space(3))) unsigned int*)l, 16, 0, 0);
}

// ---------------- elementwise f32 -> bf16 ----------------
__global__ __launch_bounds__(256) void f32_to_bf16(const float* __restrict__ in,
                                                   u16* __restrict__ out, int n) {
  int i = (blockIdx.x * 256 + threadIdx.x) * 8;
  if (i >= n) return;
  float4 a = *(const float4*)(in + i);
  float4 b = *(const float4*)(in + i + 4);
  u16x8 r;
  r[0] = f2bf(a.x); r[1] = f2bf(a.y); r[2] = f2bf(a.z); r[3] = f2bf(a.w);
  r[4] = f2bf(b.x); r[5] = f2bf(b.y); r[6] = f2bf(b.z); r[7] = f2bf(b.w);
  *(u16x8*)(out + i) = r;
}

// ---------------- tiled transpose f32 (R x C) -> bf16 (C x R), 64x64 float4 ----------------
__global__ __launch_bounds__(256) void transpose_f32_to_bf16(const float* __restrict__ in,
                                                             u16* __restrict__ out,
                                                             int R, int C) {
  __shared__ float tile[64][65];
  int c0 = blockIdx.x * 64, r0 = blockIdx.y * 64;
  int tx = threadIdx.x, ty = threadIdx.y;    // 16 x 16
#pragma unroll
  for (int i = 0; i < 64; i += 16) {
    float4 v = *(const float4*)(in + (size_t)(r0 + ty + i) * C + c0 + tx * 4);
    tile[ty + i][tx * 4 + 0] = v.x;
    tile[ty + i][tx * 4 + 1] = v.y;
    tile[ty + i][tx * 4 + 2] = v.z;
    tile[ty + i][tx * 4 + 3] = v.w;
  }
  __syncthreads();
#pragma unroll
  for (int i = 0; i < 64; i += 16) {
    u16x4 o;
#pragma unroll
    for (int j = 0; j < 4; ++j) o[j] = f2bf(tile[tx * 4 + j][ty + i]);
    *(u16x4*)(out + (size_t)(c0 + ty + i) * R + r0 + tx * 4) = o;
  }
}

// ---------------- 256xBN 4-phase full-fill GEMM (R6-proven schedule) ----------------
// C(MxN) = A(bf16 MxK rm) * Bt(bf16 NxK rm)^T.  BM=256, BN=NF*64, BK=64.
// 8 waves 4Mx2N; 4 phases/tile, quadrant = (mh: 2mf) x (nh: NF nf).
// Stage units of 8KB (512 thr x 16B): A=4/tile, B=NB=BN/64 per tile.
// P1: rd afA+bfr0, stage A(t+1)u01 [slot^1]; P2: rd bfr1, stage A(t+1)u23;
// P3: rd afB, stage B(t+2) units 0..NB-2 [slot]; P4: stage B(t+2) last unit,
// vmcnt(NB) -> A(t+1)+B(t+1) resident, B(t+2) still flying.
// Swizzle chunk ^= row&7 (128B rows), pre-swizzled source (both sides).
template <int NF, bool BF16OUT>
__global__ __launch_bounds__(512, 2) void gemm_np(const u16* __restrict__ A,
                                                  const u16* __restrict__ Bt,
                                                  void* __restrict__ Cv,
                                                  int N, int K, int NT) {
  constexpr int HN = NF * 16;
  constexpr int BN = 4 * HN;
  constexpr int NB = BN / 64;
  __shared__ u16 lsA[2][16384];
  __shared__ u16 lsB[2][BN * 64];
  const int tid = threadIdx.x;
  const int lane = tid & 63, w = tid >> 6;
  const int wm = w >> 1, wn = w & 1;
  const int l15 = lane & 15, l4 = lane >> 4;

  const int nwg = gridDim.x;
  const int cpx = nwg >> 3;
  const int bid = blockIdx.x;
  const int swz = (bid & 7) * cpx + (bid >> 3);
  const int bm = (swz & 7) * 256;
  const int bn = (swz >> 3) * BN;

  auto stageA = [&](int unit, int slot, int kt) {
    int r = tid >> 3, cp = tid & 7;
    int scp = cp ^ (r & 7);
    gload16(A + (size_t)(bm + unit * 64 + r) * K + kt * 64 + scp * 8,
            (char*)lsA[slot] + (unit * 512 + tid) * 16);
  };
  auto stageB = [&](int unit, int slot, int kt) {
    int r = tid >> 3, cp = tid & 7;
    int scp = cp ^ (r & 7);
    gload16(Bt + (size_t)(bn + unit * 64 + r) * K + kt * 64 + scp * 8,
            (char*)lsB[slot] + (unit * 512 + tid) * 16);
  };
  auto rdA = [&](int slot, int mh, int mf, int ks) -> bf16x8 {
    int r = wm * 64 + mh * 32 + mf * 16 + l15;
    int ch = (ks * 4 + l4) ^ (r & 7);
    return *(const bf16x8*)(lsA[slot] + r * 64 + ch * 8);
  };
  auto rdB = [&](int slot, int nh, int nf, int ks) -> bf16x8 {
    int r = wn * 2 * HN + nh * HN + nf * 16 + l15;
    int ch = (ks * 4 + l4) ^ (r & 7);
    return *(const bf16x8*)(lsB[slot] + r * 64 + ch * 8);
  };

#define WAIT_NB() do { if constexpr (NB == 3) asm volatile("s_waitcnt vmcnt(3)" ::: "memory"); \
                       else                   asm volatile("s_waitcnt vmcnt(2)" ::: "memory"); } while (0)

  f32x4 acc[4][2 * NF] = {};
  bf16x8 afA[2][2], afB[2][2], bfr0[NF][2], bfr1[NF][2];

  stageA(0, 0, 0); stageA(1, 0, 0); stageA(2, 0, 0); stageA(3, 0, 0);
#pragma unroll
  for (int u = 0; u < NB; ++u) stageB(u, 0, 0);
#pragma unroll
  for (int u = 0; u < NB; ++u) stageB(u, 1, 1);
  WAIT_NB();
  __builtin_amdgcn_s_barrier();

  for (int t = 0; t < NT; ++t) {
    const int s = t & 1;
    const int ktA = (t + 1 < NT) ? t + 1 : NT - 1;
    const int ktB = (t + 2 < NT) ? t + 2 : NT - 1;

    // ---- P1 ----
#pragma unroll
    for (int mf = 0; mf < 2; ++mf)
#pragma unroll
      for (int ks = 0; ks < 2; ++ks) afA[mf][ks] = rdA(s, 0, mf, ks);
#pragma unroll
    for (int nf = 0; nf < NF; ++nf)
#pragma unroll
      for (int ks = 0; ks < 2; ++ks) bfr0[nf][ks] = rdB(s, 0, nf, ks);
    stageA(0, s ^ 1, ktA); stageA(1, s ^ 1, ktA);
    __builtin_amdgcn_s_barrier();
    asm volatile("s_waitcnt lgkmcnt(0)" ::: "memory");
    __builtin_amdgcn_sched_barrier(0);
    __builtin_amdgcn_s_setprio(1);
#pragma unroll
    for (int mf = 0; mf < 2; ++mf)
#pragma unroll
      for (int nf = 0; nf < NF; ++nf) {
        acc[mf][nf] = __builtin_amdgcn_mfma_f32_16x16x32_bf16(afA[mf][0], bfr0[nf][0], acc[mf][nf], 0, 0, 0);
        acc[mf][nf] = __builtin_amdgcn_mfma_f32_16x16x32_bf16(afA[mf][1], bfr0[nf][1], acc[mf][nf], 0, 0, 0);
      }
    __builtin_amdgcn_s_setprio(0);
    __builtin_amdgcn_s_barrier();

    // ---- P2 ----
#pragma unroll
    for (int nf = 0; nf < NF; ++nf)
#pragma unroll
      for (int ks = 0; ks < 2; ++ks) bfr1[nf][ks] = rdB(s, 1, nf, ks);
    stageA(2, s ^ 1, ktA); stageA(3, s ^ 1, ktA);
    __builtin_amdgcn_s_barrier();
    asm volatile("s_waitcnt lgkmcnt(0)" ::: "memory");
    __builtin_amdgcn_sched_barrier(0);
    __builtin_amdgcn_s_setprio(1);
#pragma unroll
    for (int mf = 0; mf < 2; ++mf)
#pragma unroll
      for (int nf = 0; nf < NF; ++nf) {
        acc[mf][NF + nf] = __builtin_amdgcn_mfma_f32_16x16x32_bf16(afA[mf][0], bfr1[nf][0], acc[mf][NF + nf], 0, 0, 0);
        acc[mf][NF + nf] = __builtin_amdgcn_mfma_f32_16x16x32_bf16(afA[mf][1], bfr1[nf][1], acc[mf][NF + nf], 0, 0, 0);
      }
    __builtin_amdgcn_s_setprio(0);
    __builtin_amdgcn_s_barrier();

    // ---- P3 ----
#pragma unroll
    for (int mf = 0; mf < 2; ++mf)
#pragma unroll
      for (int ks = 0; ks < 2; ++ks) afB[mf][ks] = rdA(s, 1, mf, ks);
#pragma unroll
    for (int u = 0; u < NB - 1; ++u) stageB(u, s, ktB);
    __builtin_amdgcn_s_barrier();
    asm volatile("s_waitcnt lgkmcnt(0)" ::: "memory");
    __builtin_amdgcn_sched_barrier(0);
    __builtin_amdgcn_s_setprio(1);
#pragma unroll
    for (int mf = 0; mf < 2; ++mf)
#pragma unroll
      for (int nf = 0; nf < NF; ++nf) {
        acc[2 + mf][nf] = __builtin_amdgcn_mfma_f32_16x16x32_bf16(afB[mf][0], bfr0[nf][0], acc[2 + mf][nf], 0, 0, 0);
        acc[2 + mf][nf] = __builtin_amdgcn_mfma_f32_16x16x32_bf16(afB[mf][1], bfr0[nf][1], acc[2 + mf][nf], 0, 0, 0);
      }
    __builtin_amdgcn_s_setprio(0);
    __builtin_amdgcn_s_barrier();

    // ---- P4 ----
    stageB(NB - 1, s, ktB);
    __builtin_amdgcn_s_barrier();
    __builtin_amdgcn_s_setprio(1);
#pragma unroll
    for (int mf = 0; mf < 2; ++mf)
#pragma unroll
      for (int nf = 0; nf < NF; ++nf) {
        acc[2 + mf][NF + nf] = __builtin_amdgcn_mfma_f32_16x16x32_bf16(afB[mf][0], bfr1[nf][0], acc[2 + mf][NF + nf], 0, 0, 0);
        acc[2 + mf][NF + nf] = __builtin_amdgcn_mfma_f32_16x16x32_bf16(afB[mf][1], bfr1[nf][1], acc[2 + mf][NF + nf], 0, 0, 0);
      }
    __builtin_amdgcn_s_setprio(0);
    WAIT_NB();
    __builtin_amdgcn_s_barrier();
  }

  asm volatile("s_waitcnt vmcnt(0)" ::: "memory");

#pragma unroll
  for (int mi = 0; mi < 4; ++mi)
#pragma unroll
    for (int ni = 0; ni < 2 * NF; ++ni) {
      int row = bm + wm * 64 + mi * 16 + l4 * 4;
      int col = bn + wn * 2 * HN + ni * 16 + l15;
      if constexpr (BF16OUT) {
        u16* dst = (u16*)Cv;
#pragma unroll
        for (int j = 0; j < 4; ++j)
          dst[(size_t)(row + j) * N + col] = f2bf(acc[mi][ni][j]);
      } else {
        float* p = (float*)Cv + (size_t)row * N + col;
        p[0] = acc[mi][ni][0];
        p[(size_t)N] = acc[mi][ni][1];
        p[2 * (size_t)N] = acc[mi][ni][2];
        p[3 * (size_t)N] = acc[mi][ni][3];
      }
    }
#undef WAIT_NB
}

// ---------------- RMSNorm + RoPE + layout (bf16 qkv in; Q scaled; V transposed) -------
__global__ __launch_bounds__(256) void rope_kernel(const u16* __restrict__ qkv,
                                                   const float* __restrict__ cosb,
                                                   const float* __restrict__ sinb,
                                                   const float* __restrict__ qw,
                                                   const float* __restrict__ kw,
                                                   u16* __restrict__ Qo,
                                                   u16* __restrict__ Ko,
                                                   u16* __restrict__ Vt) {
  int wid = threadIdx.x >> 6, lane = threadIdx.x & 63;
  int item = blockIdx.x * 4 + wid;          // item = t*48 + hid
  int t = item / 48, hid = item % 48;
  const u16* x = qkv + (size_t)t * 6144 + hid * 128;
  float x1 = bf2f(x[lane]), x2 = bf2f(x[lane + 64]);
  if (hid < NQ + NKV) {
    float ss = x1 * x1 + x2 * x2;
    for (int off = 32; off; off >>= 1) ss += __shfl_xor(ss, off);
    float inv = rsqrtf(ss * (1.0f / 128.0f) + 1e-6f);
    const float* wn = (hid < NQ) ? qw : kw;
    float n1 = x1 * inv * wn[lane], n2 = x2 * inv * wn[lane + 64];
    float c1 = cosb[t * 128 + lane], s1 = sinb[t * 128 + lane];
    float c2 = cosb[t * 128 + lane + 64], s2 = sinb[t * 128 + lane + 64];
    float o1 = n1 * c1 - n2 * s1;
    float o2 = n2 * c2 + n1 * s2;
    if (hid < NQ) {
      const float scale = 0.08838834764831845f;  // fold 1/sqrt(128) into Q
      u16* q = Qo + ((size_t)hid * T_SEQ + t) * 128;
      q[lane] = f2bf(o1 * scale); q[lane + 64] = f2bf(o2 * scale);
    } else {
      int h = hid - NQ;
      u16* k = Ko + ((size_t)h * T_SEQ + t) * 128;
      k[lane] = f2bf(o1); k[lane + 64] = f2bf(o2);
    }
  } else {
    int h = hid - (NQ + NKV);
    Vt[((size_t)h * 128 + lane) * T_SEQ + t] = x[lane];
    Vt[((size_t)h * 128 + lane + 64) * T_SEQ + t] = x[lane + 64];
  }
}

// ---------------- flash attention: 4 waves/block, QBLK=64, KVBLK=64 (R9 base) ----------------
// R9-proven structure (1024 blocks for load balance). Additions: interior-tile
// fast path (skip mask compare/select when tile fully inside window for this
// wave -- wave-uniform branch), setprio(1) around QK and PV MFMA clusters (T5).
// K LDS rows 256B: swz col ^= row&7. V^T LDS rows 128B: swz ch ^= d&7.
__global__ __launch_bounds__(256) void attn_kernel(const u16* __restrict__ Q,
                                                   const u16* __restrict__ Kb,
                                                   const u16* __restrict__ Vt,
                                                   u16* __restrict__ O) {
  __shared__ u16 kls[2][64 * 128];   // 16KB per buf
  __shared__ u16 vls[2][128 * 64];   // 16KB per buf
  __shared__ u16 plds[4][16 * 72];   // per-wave P [16 q][64 k] pad to 72

  const int tid = threadIdx.x;
  const int lane = tid & 63, w = tid >> 6;
  const int l15 = lane & 15, l4 = lane >> 4;
  const int h = blockIdx.x;          // q head
  const int q0 = blockIdx.y * 64;    // block q base
  const int wq0 = q0 + w * 16;       // wave q base
  const int kvh = h >> 2;

  bf16x8 qf[4];
  {
    const u16* qrow = Q + ((size_t)h * T_SEQ + (wq0 + l15)) * DH;
    for (int ks = 0; ks < 4; ++ks)
      qf[ks] = *(const bf16x8*)(qrow + ks * 32 + l4 * 8);
  }

  f32x4 acc[8] = {};
  float m = -1e30f, lsum = 0.f;

  int ks0 = q0 - (WIN - 1); if (ks0 < 0) ks0 = 0;
  ks0 &= ~63;
  const int kend = q0;               // tile [q0, q0+63] covers the diagonal

  auto stage = [&](int b, int k0) {
#pragma unroll
    for (int c = 0; c < 4; ++c) {
      int base = w * 4096 + c * 1024;            // bytes in 16KB tile
      int idx = base / 16 + lane;                // 16B chunk index 0..1023
      {
        int row = idx >> 4;                      // K row (64 rows x 256B)
        int col = (idx & 15) ^ (row & 7);
        gload16(Kb + ((size_t)kvh * T_SEQ + k0 + row) * DH + col * 8,
                (char*)kls[b] + base);
      }
      {
        int d = idx >> 3;                        // V^T row (128 rows x 128B)
        int ch = (idx & 7) ^ (d & 7);
        gload16(Vt + ((size_t)kvh * DH + d) * T_SEQ + k0 + ch * 8,
                (char*)vls[b] + base);
      }
    }
  };

  stage(0, ks0);
  int buf = 0;
  for (int k0 = ks0; k0 <= kend; k0 += 64) {
    bool more = (k0 + 64 <= kend);
    if (more) stage(buf ^ 1, k0 + 64);
    if (more) { asm volatile("s_waitcnt vmcnt(8)" ::: "memory"); }
    else      { asm volatile("s_waitcnt vmcnt(0)" ::: "memory"); }
    __builtin_amdgcn_s_barrier();
    __builtin_amdgcn_sched_barrier(0);

    // wave skip: does [k0, k0+63] intersect [wq0-1023, wq0+15]?
    if (k0 <= wq0 + 15 && k0 + 63 >= wq0 - (WIN - 1)) {
      // ---- QK^T (swapped): S^T[k][q], A=K from LDS, B=Q regs ----
      f32x4 st[4];
      __builtin_amdgcn_s_setprio(1);
#pragma unroll
      for (int kh = 0; kh < 4; ++kh) {
        f32x4 s = {};
        int row = kh * 16 + l15;
        const char* kb = (const char*)kls[buf] + row * 256;
#pragma unroll
        for (int ks = 0; ks < 4; ++ks) {
          int chunk = (ks * 4 + l4) ^ (row & 7);
          bf16x8 kf = *(const bf16x8*)(kb + chunk * 16);
          s = __builtin_amdgcn_mfma_f32_16x16x32_bf16(kf, qf[ks], s, 0, 0, 0);
        }
        st[kh] = s;
      }
      __builtin_amdgcn_s_setprio(0);
      // ---- mask + online softmax (lane owns q = wq0+l15) ----
      const int q = wq0 + l15;
      float pv[4][4];
      float mx = -3e38f;
      // interior: all k in tile allowed for ALL q rows of this wave:
      //   k0+63 < wq0   (strict past => k>>2 <= q>>2 holds)
      //   wq0+15-k0 < WIN => k0 >= wq0-1008
      if (k0 + 64 <= wq0 && k0 >= wq0 - 1008) {
#pragma unroll
        for (int kh = 0; kh < 4; ++kh)
#pragma unroll
          for (int i = 0; i < 4; ++i) {
            pv[kh][i] = st[kh][i];
            mx = fmaxf(mx, pv[kh][i]);
          }
      } else {
#pragma unroll
        for (int kh = 0; kh < 4; ++kh)
#pragma unroll
          for (int i = 0; i < 4; ++i) {
            int k = k0 + kh * 16 + l4 * 4 + i;
            bool ok = ((k >> 2) <= (q >> 2)) && (q - k < WIN);
            float s = ok ? st[kh][i] : -3e38f;
            pv[kh][i] = s;
            mx = fmaxf(mx, s);
          }
      }
      mx = fmaxf(mx, __shfl_xor(mx, 16));
      mx = fmaxf(mx, __shfl_xor(mx, 32));
      if (!__all(mx <= m + 8.f)) {      // defer-max
        float mn = fmaxf(m, mx);
        float sc = __expf(m - mn);
        m = mn;
        lsum *= sc;
#pragma unroll
        for (int nt = 0; nt < 8; ++nt)
#pragma unroll
          for (int i = 0; i < 4; ++i) acc[nt][i] *= sc;
      }
      float rs = 0.f;
#pragma unroll
      for (int kh = 0; kh < 4; ++kh)
#pragma unroll
        for (int i = 0; i < 4; ++i) {
          float p = __expf(pv[kh][i] - m);
          pv[kh][i] = p;
          rs += p;
        }
      rs += __shfl_xor(rs, 16);
      rs += __shfl_xor(rs, 32);
      lsum += rs;
      // ---- pack P -> per-wave LDS [16 q][64 k] ----
      u16* pw = plds[w];
#pragma unroll
      for (int kh = 0; kh < 4; ++kh) {
        unsigned int d0 = (unsigned int)f2bf(pv[kh][0]) | ((unsigned int)f2bf(pv[kh][1]) << 16);
        unsigned int d1 = (unsigned int)f2bf(pv[kh][2]) | ((unsigned int)f2bf(pv[kh][3]) << 16);
        *(unsigned int*)(pw + l15 * 72 + kh * 16 + l4 * 4) = d0;
        *(unsigned int*)(pw + l15 * 72 + kh * 16 + l4 * 4 + 2) = d1;
      }
      bf16x8 pf0 = *(const bf16x8*)(pw + l15 * 72 + l4 * 8);
      bf16x8 pf1 = *(const bf16x8*)(pw + l15 * 72 + 32 + l4 * 8);
      // ---- PV: O^T += V^T * P^T (A = V^T from LDS, B = P), 2 K=32 halves ----
      __builtin_amdgcn_s_setprio(1);
#pragma unroll
      for (int nt = 0; nt < 8; ++nt) {
        int d = nt * 16 + l15;
        int ch0 = l4 ^ (d & 7);
        int ch1 = (4 + l4) ^ (d & 7);
        bf16x8 vf0 = *(const bf16x8*)((const char*)vls[buf] + d * 128 + ch0 * 16);
        bf16x8 vf1 = *(const bf16x8*)((const char*)vls[buf] + d * 128 + ch1 * 16);
        acc[nt] = __builtin_amdgcn_mfma_f32_16x16x32_bf16(vf0, pf0, acc[nt], 0, 0, 0);
        acc[nt] = __builtin_amdgcn_mfma_f32_16x16x32_bf16(vf1, pf1, acc[nt], 0, 0, 0);
      }
      __builtin_amdgcn_s_setprio(0);
    }
    __builtin_amdgcn_sched_barrier(0);
    __builtin_amdgcn_s_barrier();
    buf ^= 1;
  }

  // ---- epilogue ----
  float inv = 1.0f / lsum;
#pragma unroll
  for (int nt = 0; nt < 8; ++nt) {
    u16x4 o;
#pragma unroll
    for (int i = 0; i < 4; ++i) o[i] = f2bf(acc[nt][i] * inv);
    *(u16x4*)(O + (size_t)(wq0 + l15) * (NQ * DH) + h * DH + nt * 16 + l4 * 4) = o;
  }
}

extern "C" void kernel_launch(void* const* d_in, const int* in_sizes, int n_in,
                              void* d_out, int out_size, void* d_ws, size_t ws_size,
                              hipStream_t stream) {
  const float* hidden = (const float*)d_in[0];
  const float* cosb   = (const float*)d_in[1];
  const float* sinb   = (const float*)d_in[2];
  const float* w_qkv  = (const float*)d_in[3];
  const float* qnw    = (const float*)d_in[4];
  const float* knw    = (const float*)d_in[5];
  const float* w_o    = (const float*)d_in[6];
  float* out = (float*)d_out;
  char* ws = (char*)d_ws;

  u16*   wqkvT  = (u16*)(ws);                        // [0, 48M)
  u16*   hid_bf = (u16*)(ws + ((size_t)48 << 20));   // [48M, 64M)
  u16*   qkv_bf = (u16*)(ws + ((size_t)64 << 20));   // [64M, 88M) bf16 qkv (24MB)
  u16*   q_bf   = (u16*)(ws + ((size_t)112 << 20));  // 16MB
  u16*   k_bf   = (u16*)(ws + ((size_t)128 << 20));  // 4MB
  u16*   vt_bf  = (u16*)(ws + ((size_t)132 << 20));  // 4MB
  u16*   attn_bf= (u16*)(ws + ((size_t)48 << 20));   // reuse hid_bf region
  u16*   woT    = (u16*)(ws);                        // reuse wqkvT region

  f32_to_bf16<<<4096, 256, 0, stream>>>(hidden, hid_bf, T_SEQ * HID);
  transpose_f32_to_bf16<<<dim3(96, 64), dim3(16, 16), 0, stream>>>(w_qkv, wqkvT, HID, 6144);
  // gemm1: 2048x6144x4096, BN=192 -> grid 8x32 = 256 blocks (full fill), bf16 out
  gemm_np<3, true><<<256, 512, 0, stream>>>(hid_bf, wqkvT, qkv_bf, 6144, HID, 64);
  transpose_f32_to_bf16<<<dim3(64, 64), dim3(16, 16), 0, stream>>>(w_o, woT, NQ * DH, HID);
  rope_kernel<<<(T_SEQ * 48) / 4, 256, 0, stream>>>(qkv_bf, cosb, sinb, qnw, knw, q_bf, k_bf, vt_bf);
  attn_kernel<<<dim3(NQ, T_SEQ / 64), 256, 0, stream>>>(q_bf, k_bf, vt_bf, attn_bf);
  // gemm2: 2048x4096x4096, BN=128 -> grid 8x32 = 256 blocks (full fill), f32 out
  gemm_np<2, false><<<256, 512, 0, stream>>>(attn_bf, woT, out, HID, NQ * DH, 64);
}

// Round 13
// 319.861 us; speedup vs baseline: 1.1627x; 1.0323x over previous
//
#include <hip/hip_runtime.h>
#include <hip/hip_bf16.h>

typedef unsigned short u16;
typedef __attribute__((ext_vector_type(8))) short bf16x8;
typedef __attribute__((ext_vector_type(4))) float f32x4;
typedef __attribute__((ext_vector_type(8))) u16 u16x8;
typedef __attribute__((ext_vector_type(4))) u16 u16x4;

#define T_SEQ 2048
#define HID 4096
#define NQ 32
#define NKV 8
#define DH 128
#define WIN 1024

__device__ __forceinline__ u16 f2bf(float f) {
  union { float f; unsigned int u; } v; v.f = f;
  unsigned int u = v.u;
  unsigned int r = (u + 0x7FFFu + ((u >> 16) & 1u)) >> 16;
  return (u16)r;
}
__device__ __forceinline__ float bf2f(u16 b) {
  union { unsigned int u; float f; } v; v.u = ((unsigned int)b) << 16;
  return v.f;
}

__device__ __forceinline__ void gload16(const void* g, void* l) {
  __builtin_amdgcn_global_load_lds(
      (const __attribute__((address_space(1))) unsigned int*)g,
      (__attribute__((address_space(3))) unsigned int*)l, 16, 0, 0);
}

// ---------------- elementwise f32 -> bf16 ----------------
__global__ __launch_bounds__(256) void f32_to_bf16(const float* __restrict__ in,
                                                   u16* __restrict__ out, int n) {
  int i = (blockIdx.x * 256 + threadIdx.x) * 8;
  if (i >= n) return;
  float4 a = *(const float4*)(in + i);
  float4 b = *(const float4*)(in + i + 4);
  u16x8 r;
  r[0] = f2bf(a.x); r[1] = f2bf(a.y); r[2] = f2bf(a.z); r[3] = f2bf(a.w);
  r[4] = f2bf(b.x); r[5] = f2bf(b.y); r[6] = f2bf(b.z); r[7] = f2bf(b.w);
  *(u16x8*)(out + i) = r;
}

// ---------------- tiled transpose f32 (R x C) -> bf16 (C x R), 64x64 float4 ----------------
__global__ __launch_bounds__(256) void transpose_f32_to_bf16(const float* __restrict__ in,
                                                             u16* __restrict__ out,
                                                             int R, int C) {
  __shared__ float tile[64][65];
  int c0 = blockIdx.x * 64, r0 = blockIdx.y * 64;
  int tx = threadIdx.x, ty = threadIdx.y;    // 16 x 16
#pragma unroll
  for (int i = 0; i < 64; i += 16) {
    float4 v = *(const float4*)(in + (size_t)(r0 + ty + i) * C + c0 + tx * 4);
    tile[ty + i][tx * 4 + 0] = v.x;
    tile[ty + i][tx * 4 + 1] = v.y;
    tile[ty + i][tx * 4 + 2] = v.z;
    tile[ty + i][tx * 4 + 3] = v.w;
  }
  __syncthreads();
#pragma unroll
  for (int i = 0; i < 64; i += 16) {
    u16x4 o;
#pragma unroll
    for (int j = 0; j < 4; ++j) o[j] = f2bf(tile[tx * 4 + j][ty + i]);
    *(u16x4*)(out + (size_t)(c0 + ty + i) * R + r0 + tx * 4) = o;
  }
}

// ---------------- 256xBN 2-window full-fill GEMM ----------------
// Same data flow / issue order / wait arithmetic as the proven 4-phase gemm_np
// (R6/R9), but the 4 quadrant phases are merged into 2 windows: half the
// barriers (8->4 per tile), double the MFMA cluster (8*NF per window).
// W1: rd afA(mh0) + ALL B frags | stage A(t+1) u0..3 [slot^1] | barrier |
//     lgkm0 | MFMA mh0 x all nf | barrier
// W2: rd afB(mh1) | stage B(t+2) u0..NB-1 [slot] | barrier | lgkm0 |
//     MFMA mh1 x all nf | vmcnt(NB) | barrier
// Hazards: every reader drains (lgkm0) before its window-end barrier; each
// stage targets a region whose last reader window ended >=1 barrier earlier
// (A[slot^1] last read in W2(t-1); B[slot] last read in W1(t)). vmcnt(NB) at
// end-W2 retires A(t+1)+B(t+1), leaves B(t+2) flying. Tail clamps (dummies).
// Swizzle chunk ^= row&7 (128B rows), pre-swizzled source (both sides).
template <int NF, bool BF16OUT>
__global__ __launch_bounds__(512, 2) void gemm_2w(const u16* __restrict__ A,
                                                  const u16* __restrict__ Bt,
                                                  void* __restrict__ Cv,
                                                  int N, int K, int NT) {
  constexpr int HN = NF * 16;
  constexpr int BN = 4 * HN;
  constexpr int NB = BN / 64;
  __shared__ u16 lsA[2][16384];
  __shared__ u16 lsB[2][BN * 64];
  const int tid = threadIdx.x;
  const int lane = tid & 63, w = tid >> 6;
  const int wm = w >> 1, wn = w & 1;
  const int l15 = lane & 15, l4 = lane >> 4;

  const int nwg = gridDim.x;
  const int cpx = nwg >> 3;
  const int bid = blockIdx.x;
  const int swz = (bid & 7) * cpx + (bid >> 3);
  const int bm = (swz & 7) * 256;
  const int bn = (swz >> 3) * BN;

  auto stageA = [&](int unit, int slot, int kt) {
    int r = tid >> 3, cp = tid & 7;
    int scp = cp ^ (r & 7);
    gload16(A + (size_t)(bm + unit * 64 + r) * K + kt * 64 + scp * 8,
            (char*)lsA[slot] + (unit * 512 + tid) * 16);
  };
  auto stageB = [&](int unit, int slot, int kt) {
    int r = tid >> 3, cp = tid & 7;
    int scp = cp ^ (r & 7);
    gload16(Bt + (size_t)(bn + unit * 64 + r) * K + kt * 64 + scp * 8,
            (char*)lsB[slot] + (unit * 512 + tid) * 16);
  };
  auto rdA = [&](int slot, int mh, int mf, int ks) -> bf16x8 {
    int r = wm * 64 + mh * 32 + mf * 16 + l15;
    int ch = (ks * 4 + l4) ^ (r & 7);
    return *(const bf16x8*)(lsA[slot] + r * 64 + ch * 8);
  };
  auto rdB = [&](int slot, int nh, int nf, int ks) -> bf16x8 {
    int r = wn * 2 * HN + nh * HN + nf * 16 + l15;
    int ch = (ks * 4 + l4) ^ (r & 7);
    return *(const bf16x8*)(lsB[slot] + r * 64 + ch * 8);
  };

#define WAIT_NB() do { if constexpr (NB == 3) asm volatile("s_waitcnt vmcnt(3)" ::: "memory"); \
                       else                   asm volatile("s_waitcnt vmcnt(2)" ::: "memory"); } while (0)

  f32x4 acc[4][2 * NF] = {};
  bf16x8 afA[2][2], afB[2][2], bfr[2 * NF][2];

  // prologue: A(0) 4u + B(0) NBu + B(1) NBu; vmcnt(NB) -> tile0 resident
  stageA(0, 0, 0); stageA(1, 0, 0); stageA(2, 0, 0); stageA(3, 0, 0);
#pragma unroll
  for (int u = 0; u < NB; ++u) stageB(u, 0, 0);
#pragma unroll
  for (int u = 0; u < NB; ++u) stageB(u, 1, 1);
  WAIT_NB();
  __builtin_amdgcn_s_barrier();

  for (int t = 0; t < NT; ++t) {
    const int s = t & 1;
    const int ktA = (t + 1 < NT) ? t + 1 : NT - 1;
    const int ktB = (t + 2 < NT) ? t + 2 : NT - 1;

    // ---- W1: rd afA + all B; stage A(t+1); MFMA mh0 x all ----
#pragma unroll
    for (int mf = 0; mf < 2; ++mf)
#pragma unroll
      for (int ks = 0; ks < 2; ++ks) afA[mf][ks] = rdA(s, 0, mf, ks);
#pragma unroll
    for (int nf = 0; nf < NF; ++nf)
#pragma unroll
      for (int ks = 0; ks < 2; ++ks) {
        bfr[nf][ks] = rdB(s, 0, nf, ks);
        bfr[NF + nf][ks] = rdB(s, 1, nf, ks);
      }
    stageA(0, s ^ 1, ktA); stageA(1, s ^ 1, ktA);
    stageA(2, s ^ 1, ktA); stageA(3, s ^ 1, ktA);
    __builtin_amdgcn_s_barrier();
    asm volatile("s_waitcnt lgkmcnt(0)" ::: "memory");
    __builtin_amdgcn_sched_barrier(0);
    __builtin_amdgcn_s_setprio(1);
#pragma unroll
    for (int mf = 0; mf < 2; ++mf)
#pragma unroll
      for (int nf = 0; nf < 2 * NF; ++nf) {
        acc[mf][nf] = __builtin_amdgcn_mfma_f32_16x16x32_bf16(afA[mf][0], bfr[nf][0], acc[mf][nf], 0, 0, 0);
        acc[mf][nf] = __builtin_amdgcn_mfma_f32_16x16x32_bf16(afA[mf][1], bfr[nf][1], acc[mf][nf], 0, 0, 0);
      }
    __builtin_amdgcn_s_setprio(0);
    __builtin_amdgcn_s_barrier();

    // ---- W2: rd afB; stage B(t+2); MFMA mh1 x all; vmcnt(NB) ----
#pragma unroll
    for (int mf = 0; mf < 2; ++mf)
#pragma unroll
      for (int ks = 0; ks < 2; ++ks) afB[mf][ks] = rdA(s, 1, mf, ks);
#pragma unroll
    for (int u = 0; u < NB; ++u) stageB(u, s, ktB);
    __builtin_amdgcn_s_barrier();
    asm volatile("s_waitcnt lgkmcnt(0)" ::: "memory");
    __builtin_amdgcn_sched_barrier(0);
    __builtin_amdgcn_s_setprio(1);
#pragma unroll
    for (int mf = 0; mf < 2; ++mf)
#pragma unroll
      for (int nf = 0; nf < 2 * NF; ++nf) {
        acc[2 + mf][nf] = __builtin_amdgcn_mfma_f32_16x16x32_bf16(afB[mf][0], bfr[nf][0], acc[2 + mf][nf], 0, 0, 0);
        acc[2 + mf][nf] = __builtin_amdgcn_mfma_f32_16x16x32_bf16(afB[mf][1], bfr[nf][1], acc[2 + mf][nf], 0, 0, 0);
      }
    __builtin_amdgcn_s_setprio(0);
    WAIT_NB();
    __builtin_amdgcn_s_barrier();
  }

  asm volatile("s_waitcnt vmcnt(0)" ::: "memory");

#pragma unroll
  for (int mi = 0; mi < 4; ++mi)
#pragma unroll
    for (int ni = 0; ni < 2 * NF; ++ni) {
      int row = bm + wm * 64 + mi * 16 + l4 * 4;
      int col = bn + wn * 2 * HN + ni * 16 + l15;
      if constexpr (BF16OUT) {
        u16* dst = (u16*)Cv;
#pragma unroll
        for (int j = 0; j < 4; ++j)
          dst[(size_t)(row + j) * N + col] = f2bf(acc[mi][ni][j]);
      } else {
        float* p = (float*)Cv + (size_t)row * N + col;
        p[0] = acc[mi][ni][0];
        p[(size_t)N] = acc[mi][ni][1];
        p[2 * (size_t)N] = acc[mi][ni][2];
        p[3 * (size_t)N] = acc[mi][ni][3];
      }
    }
#undef WAIT_NB
}

// ---------------- RMSNorm + RoPE + layout (bf16 qkv in; Q scaled; V transposed) -------
__global__ __launch_bounds__(256) void rope_kernel(const u16* __restrict__ qkv,
                                                   const float* __restrict__ cosb,
                                                   const float* __restrict__ sinb,
                                                   const float* __restrict__ qw,
                                                   const float* __restrict__ kw,
                                                   u16* __restrict__ Qo,
                                                   u16* __restrict__ Ko,
                                                   u16* __restrict__ Vt) {
  int wid = threadIdx.x >> 6, lane = threadIdx.x & 63;
  int item = blockIdx.x * 4 + wid;          // item = t*48 + hid
  int t = item / 48, hid = item % 48;
  const u16* x = qkv + (size_t)t * 6144 + hid * 128;
  float x1 = bf2f(x[lane]), x2 = bf2f(x[lane + 64]);
  if (hid < NQ + NKV) {
    float ss = x1 * x1 + x2 * x2;
    for (int off = 32; off; off >>= 1) ss += __shfl_xor(ss, off);
    float inv = rsqrtf(ss * (1.0f / 128.0f) + 1e-6f);
    const float* wn = (hid < NQ) ? qw : kw;
    float n1 = x1 * inv * wn[lane], n2 = x2 * inv * wn[lane + 64];
    float c1 = cosb[t * 128 + lane], s1 = sinb[t * 128 + lane];
    float c2 = cosb[t * 128 + lane + 64], s2 = sinb[t * 128 + lane + 64];
    float o1 = n1 * c1 - n2 * s1;
    float o2 = n2 * c2 + n1 * s2;
    if (hid < NQ) {
      const float scale = 0.08838834764831845f;  // fold 1/sqrt(128) into Q
      u16* q = Qo + ((size_t)hid * T_SEQ + t) * 128;
      q[lane] = f2bf(o1 * scale); q[lane + 64] = f2bf(o2 * scale);
    } else {
      int h = hid - NQ;
      u16* k = Ko + ((size_t)h * T_SEQ + t) * 128;
      k[lane] = f2bf(o1); k[lane + 64] = f2bf(o2);
    }
  } else {
    int h = hid - (NQ + NKV);
    Vt[((size_t)h * 128 + lane) * T_SEQ + t] = x[lane];
    Vt[((size_t)h * 128 + lane + 64) * T_SEQ + t] = x[lane + 64];
  }
}

// ---------------- flash attention: 4 waves/block, QBLK=64, KVBLK=64 (R11 form) ----------------
// R9-proven structure (1024 blocks for load balance) + interior-tile fast path
// + setprio around MFMA clusters.
// K LDS rows 256B: swz col ^= row&7. V^T LDS rows 128B: swz ch ^= d&7.
__global__ __launch_bounds__(256) void attn_kernel(const u16* __restrict__ Q,
                                                   const u16* __restrict__ Kb,
                                                   const u16* __restrict__ Vt,
                                                   u16* __restrict__ O) {
  __shared__ u16 kls[2][64 * 128];   // 16KB per buf
  __shared__ u16 vls[2][128 * 64];   // 16KB per buf
  __shared__ u16 plds[4][16 * 72];   // per-wave P [16 q][64 k] pad to 72

  const int tid = threadIdx.x;
  const int lane = tid & 63, w = tid >> 6;
  const int l15 = lane & 15, l4 = lane >> 4;
  const int h = blockIdx.x;          // q head
  const int q0 = blockIdx.y * 64;    // block q base
  const int wq0 = q0 + w * 16;       // wave q base
  const int kvh = h >> 2;

  bf16x8 qf[4];
  {
    const u16* qrow = Q + ((size_t)h * T_SEQ + (wq0 + l15)) * DH;
    for (int ks = 0; ks < 4; ++ks)
      qf[ks] = *(const bf16x8*)(qrow + ks * 32 + l4 * 8);
  }

  f32x4 acc[8] = {};
  float m = -1e30f, lsum = 0.f;

  int ks0 = q0 - (WIN - 1); if (ks0 < 0) ks0 = 0;
  ks0 &= ~63;
  const int kend = q0;               // tile [q0, q0+63] covers the diagonal

  auto stage = [&](int b, int k0) {
#pragma unroll
    for (int c = 0; c < 4; ++c) {
      int base = w * 4096 + c * 1024;            // bytes in 16KB tile
      int idx = base / 16 + lane;                // 16B chunk index 0..1023
      {
        int row = idx >> 4;                      // K row (64 rows x 256B)
        int col = (idx & 15) ^ (row & 7);
        gload16(Kb + ((size_t)kvh * T_SEQ + k0 + row) * DH + col * 8,
                (char*)kls[b] + base);
      }
      {
        int d = idx >> 3;                        // V^T row (128 rows x 128B)
        int ch = (idx & 7) ^ (d & 7);
        gload16(Vt + ((size_t)kvh * DH + d) * T_SEQ + k0 + ch * 8,
                (char*)vls[b] + base);
      }
    }
  };

  stage(0, ks0);
  int buf = 0;
  for (int k0 = ks0; k0 <= kend; k0 += 64) {
    bool more = (k0 + 64 <= kend);
    if (more) stage(buf ^ 1, k0 + 64);
    if (more) { asm volatile("s_waitcnt vmcnt(8)" ::: "memory"); }
    else      { asm volatile("s_waitcnt vmcnt(0)" ::: "memory"); }
    __builtin_amdgcn_s_barrier();
    __builtin_amdgcn_sched_barrier(0);

    // wave skip: does [k0, k0+63] intersect [wq0-1023, wq0+15]?
    if (k0 <= wq0 + 15 && k0 + 63 >= wq0 - (WIN - 1)) {
      // ---- QK^T (swapped): S^T[k][q], A=K from LDS, B=Q regs ----
      f32x4 st[4];
      __builtin_amdgcn_s_setprio(1);
#pragma unroll
      for (int kh = 0; kh < 4; ++kh) {
        f32x4 s = {};
        int row = kh * 16 + l15;
        const char* kb = (const char*)kls[buf] + row * 256;
#pragma unroll
        for (int ks = 0; ks < 4; ++ks) {
          int chunk = (ks * 4 + l4) ^ (row & 7);
          bf16x8 kf = *(const bf16x8*)(kb + chunk * 16);
          s = __builtin_amdgcn_mfma_f32_16x16x32_bf16(kf, qf[ks], s, 0, 0, 0);
        }
        st[kh] = s;
      }
      __builtin_amdgcn_s_setprio(0);
      // ---- mask + online softmax (lane owns q = wq0+l15) ----
      const int q = wq0 + l15;
      float pv[4][4];
      float mx = -3e38f;
      // interior: all k in tile allowed for ALL q rows of this wave
      if (k0 + 64 <= wq0 && k0 >= wq0 - 1008) {
#pragma unroll
        for (int kh = 0; kh < 4; ++kh)
#pragma unroll
          for (int i = 0; i < 4; ++i) {
            pv[kh][i] = st[kh][i];
            mx = fmaxf(mx, pv[kh][i]);
          }
      } else {
#pragma unroll
        for (int kh = 0; kh < 4; ++kh)
#pragma unroll
          for (int i = 0; i < 4; ++i) {
            int k = k0 + kh * 16 + l4 * 4 + i;
            bool ok = ((k >> 2) <= (q >> 2)) && (q - k < WIN);
            float s = ok ? st[kh][i] : -3e38f;
            pv[kh][i] = s;
            mx = fmaxf(mx, s);
          }
      }
      mx = fmaxf(mx, __shfl_xor(mx, 16));
      mx = fmaxf(mx, __shfl_xor(mx, 32));
      if (!__all(mx <= m + 8.f)) {      // defer-max
        float mn = fmaxf(m, mx);
        float sc = __expf(m - mn);
        m = mn;
        lsum *= sc;
#pragma unroll
        for (int nt = 0; nt < 8; ++nt)
#pragma unroll
          for (int i = 0; i < 4; ++i) acc[nt][i] *= sc;
      }
      float rs = 0.f;
#pragma unroll
      for (int kh = 0; kh < 4; ++kh)
#pragma unroll
        for (int i = 0; i < 4; ++i) {
          float p = __expf(pv[kh][i] - m);
          pv[kh][i] = p;
          rs += p;
        }
      rs += __shfl_xor(rs, 16);
      rs += __shfl_xor(rs, 32);
      lsum += rs;
      // ---- pack P -> per-wave LDS [16 q][64 k] ----
      u16* pw = plds[w];
#pragma unroll
      for (int kh = 0; kh < 4; ++kh) {
        unsigned int d0 = (unsigned int)f2bf(pv[kh][0]) | ((unsigned int)f2bf(pv[kh][1]) << 16);
        unsigned int d1 = (unsigned int)f2bf(pv[kh][2]) | ((unsigned int)f2bf(pv[kh][3]) << 16);
        *(unsigned int*)(pw + l15 * 72 + kh * 16 + l4 * 4) = d0;
        *(unsigned int*)(pw + l15 * 72 + kh * 16 + l4 * 4 + 2) = d1;
      }
      bf16x8 pf0 = *(const bf16x8*)(pw + l15 * 72 + l4 * 8);
      bf16x8 pf1 = *(const bf16x8*)(pw + l15 * 72 + 32 + l4 * 8);
      // ---- PV: O^T += V^T * P^T (A = V^T from LDS, B = P), 2 K=32 halves ----
      __builtin_amdgcn_s_setprio(1);
#pragma unroll
      for (int nt = 0; nt < 8; ++nt) {
        int d = nt * 16 + l15;
        int ch0 = l4 ^ (d & 7);
        int ch1 = (4 + l4) ^ (d & 7);
        bf16x8 vf0 = *(const bf16x8*)((const char*)vls[buf] + d * 128 + ch0 * 16);
        bf16x8 vf1 = *(const bf16x8*)((const char*)vls[buf] + d * 128 + ch1 * 16);
        acc[nt] = __builtin_amdgcn_mfma_f32_16x16x32_bf16(vf0, pf0, acc[nt], 0, 0, 0);
        acc[nt] = __builtin_amdgcn_mfma_f32_16x16x32_bf16(vf1, pf1, acc[nt], 0, 0, 0);
      }
      __builtin_amdgcn_s_setprio(0);
    }
    __builtin_amdgcn_sched_barrier(0);
    __builtin_amdgcn_s_barrier();
    buf ^= 1;
  }

  // ---- epilogue ----
  float inv = 1.0f / lsum;
#pragma unroll
  for (int nt = 0; nt < 8; ++nt) {
    u16x4 o;
#pragma unroll
    for (int i = 0; i < 4; ++i) o[i] = f2bf(acc[nt][i] * inv);
    *(u16x4*)(O + (size_t)(wq0 + l15) * (NQ * DH) + h * DH + nt * 16 + l4 * 4) = o;
  }
}

extern "C" void kernel_launch(void* const* d_in, const int* in_sizes, int n_in,
                              void* d_out, int out_size, void* d_ws, size_t ws_size,
                              hipStream_t stream) {
  const float* hidden = (const float*)d_in[0];
  const float* cosb   = (const float*)d_in[1];
  const float* sinb   = (const float*)d_in[2];
  const float* w_qkv  = (const float*)d_in[3];
  const float* qnw    = (const float*)d_in[4];
  const float* knw    = (const float*)d_in[5];
  const float* w_o    = (const float*)d_in[6];
  float* out = (float*)d_out;
  char* ws = (char*)d_ws;

  u16*   wqkvT  = (u16*)(ws);                        // [0, 48M)
  u16*   hid_bf = (u16*)(ws + ((size_t)48 << 20));   // [48M, 64M)
  u16*   qkv_bf = (u16*)(ws + ((size_t)64 << 20));   // [64M, 88M) bf16 qkv (24MB)
  u16*   q_bf   = (u16*)(ws + ((size_t)112 << 20));  // 16MB
  u16*   k_bf   = (u16*)(ws + ((size_t)128 << 20));  // 4MB
  u16*   vt_bf  = (u16*)(ws + ((size_t)132 << 20));  // 4MB
  u16*   attn_bf= (u16*)(ws + ((size_t)48 << 20));   // reuse hid_bf region
  u16*   woT    = (u16*)(ws);                        // reuse wqkvT region

  f32_to_bf16<<<4096, 256, 0, stream>>>(hidden, hid_bf, T_SEQ * HID);
  transpose_f32_to_bf16<<<dim3(96, 64), dim3(16, 16), 0, stream>>>(w_qkv, wqkvT, HID, 6144);
  // gemm1: 2048x6144x4096, BN=192 -> grid 8x32 = 256 blocks (full fill), bf16 out
  gemm_2w<3, true><<<256, 512, 0, stream>>>(hid_bf, wqkvT, qkv_bf, 6144, HID, 64);
  transpose_f32_to_bf16<<<dim3(64, 64), dim3(16, 16), 0, stream>>>(w_o, woT, NQ * DH, HID);
  rope_kernel<<<(T_SEQ * 48) / 4, 256, 0, stream>>>(qkv_bf, cosb, sinb, qnw, knw, q_bf, k_bf, vt_bf);
  attn_kernel<<<dim3(NQ, T_SEQ / 64), 256, 0, stream>>>(q_bf, k_bf, vt_bf, attn_bf);
  // gemm2: 2048x4096x4096, BN=128 -> grid 8x32 = 256 blocks (full fill), f32 out
  gemm_2w<2, false><<<256, 512, 0, stream>>>(attn_bf, woT, out, HID, NQ * DH, 64);
}